// Round 24
// baseline (82.265 us; speedup 1.0000x reference)
//
#include <hip/hip_runtime.h>
#include <hip/hip_bf16.h>
#include <math.h>

// SkipGRU on MI355X, round 24: ride gemm chunks inside step dispatches.
// r22/r23 falsified step-fusion (fused h1 block = ~96 per-thread global
// loads = +9us; third confirmation of the serialized per-thread-load law).
// This round reverts all kernels to r21 (58.0us) and adds ONE change with
// zero per-thread loads: step dispatches c=0..5 carry 48 extra block-uniform
// WGs computing MX chunk c+2 with the byte-identical gemm tile (steps use
// only 128/256 CUs -> the gemm rides idle capacity). Node 2 shrinks to
// chunks 0-1 (96 WGs). Chunk c+2 is written >= 1 full dispatch boundary
// before its reader (step c+2) -> visibility guaranteed. Steps 6-7 use the
// UNTOUCHED r21 gru_step.
//
// Only chain j=23 contributes to outputs[:, -1, :] (t=191 = chunk 7 lane 23):
// 8 sequential GRU steps over x[:, c*24+23, :], h[256,512].
//
// mfma_f32_16x16x32_bf16 layouts (learn_hip m89-verified, r4-r23 validated):
//   A: lane l holds A[l&15][(l>>4)*8 + j]
//   B: lane l holds B[(l>>4)*8 + j][l&15]  (B^T row-major -> contiguous load)
//   D: lane l reg q -> row (l>>4)*4+q, col l&15
//
// Swizzle rule (h and B): global row of 1024B stores byte o at o^((row&7)<<4);
// global_load_lds copies rows linearly; ds_read applies the same XOR
// (involution) -> conflict-free LDS reads (guide §6 G4 + m173; r13-r21 proven).

typedef float f32x4 __attribute__((ext_vector_type(4)));
typedef short short8 __attribute__((ext_vector_type(8)));

#define BB 256
#define UU 512
#define KK 512
#define N3 1536

__device__ __forceinline__ float sigmoidf_(float s) {
    return 1.0f / (1.0f + __expf(-s));
}

// Fused prologue: blocks [0,768) transpose ker, [768,1536) transpose rker,
// [1536,2048) gather+convert x.  (r21, frozen)
__global__ __launch_bounds__(256)
void prologue(const float* __restrict__ ker, const float* __restrict__ rker,
              const float* __restrict__ x,
              __hip_bfloat16* __restrict__ Kt, __hip_bfloat16* __restrict__ Rtb,
              __hip_bfloat16* __restrict__ Xb)
{
    __shared__ float tile[32][33];
    const int blk = blockIdx.x;
    const int tid = threadIdx.x;
    if (blk < 1536) {
        const float* W = (blk < 768) ? ker : rker;
        __hip_bfloat16* Wt = (blk < 768) ? Kt : Rtb;
        const int b = (blk < 768) ? blk : blk - 768;
        const int xx = tid & 31, yy = tid >> 5;           // (32, 8)
        const int c0 = (b % 48) * 32;                     // C = 1536
        const int r0 = (b / 48) * 32;                     // R = 512
        #pragma unroll
        for (int i = 0; i < 32; i += 8)
            tile[yy + i][xx] = W[(long)(r0 + yy + i) * N3 + c0 + xx];
        __syncthreads();
        #pragma unroll
        for (int i = 0; i < 32; i += 8)
            Wt[(long)(c0 + yy + i) * KK + r0 + xx] = __float2bfloat16(tile[xx][yy + i]);
    } else {
        const int idx = (blk - 1536) * 256 + tid;         // one thread per 8 elems
        const int e = idx * 8;
        const int m = e >> 9;              // 0..2047 = c*256+b
        const int kk = e & 511;
        const int bb = m & 255, c = m >> 8;
        const float* src = x + (long)bb * (192 * 512) + (long)(c * 24 + 23) * 512 + kk;
        float4 v0 = *(const float4*)src;
        float4 v1 = *(const float4*)(src + 4);
        __hip_bfloat16* dst = Xb + (long)m * 512 + kk;
        dst[0] = __float2bfloat16(v0.x);
        dst[1] = __float2bfloat16(v0.y);
        dst[2] = __float2bfloat16(v0.z);
        dst[3] = __float2bfloat16(v0.w);
        dst[4] = __float2bfloat16(v1.x);
        dst[5] = __float2bfloat16(v1.y);
        dst[6] = __float2bfloat16(v1.z);
        dst[7] = __float2bfloat16(v1.w);
    }
}

// One 64x128 gemm tile (r21 gemm_mx body, byte-identical arithmetic).
// m0/n0 absolute; Als 4KB, Bls 8KB scratch.
__device__ __forceinline__ void gemm_tile_dev(
    const __hip_bfloat16* __restrict__ A, const __hip_bfloat16* __restrict__ Bt,
    const float* __restrict__ bias, float* __restrict__ C,
    int m0, int n0, char* Als, char* Bls)
{
    const int tid = threadIdx.x;
    const int lane = tid & 63;
    const int w = tid >> 6;
    const int wm = w >> 1, wn = w & 1;
    const int lr = lane & 15;
    const int hi = lane >> 4;
    const int srow = lane >> 2;
    const int scol = (lane & 3) * 16;

    const char* Ab = (const char*)A;
    const char* Bb = (const char*)Bt;

    f32x4 acc[2][4];
    #pragma unroll
    for (int i = 0; i < 2; ++i)
        #pragma unroll
        for (int j = 0; j < 4; ++j) acc[i][j] = {0.f, 0.f, 0.f, 0.f};

    for (int ks = 0; ks < 16; ++ks) {
        const long k0b = (long)ks * 64;
        __syncthreads();
        __builtin_amdgcn_global_load_lds(
            (const __attribute__((address_space(1))) unsigned int*)
                (Ab + (long)(m0 + w * 16 + srow) * 1024 + k0b + scol),
            (__attribute__((address_space(3))) unsigned int*)(Als + w * 1024),
            16, 0, 0);
        #pragma unroll
        for (int j = 0; j < 2; ++j)
            __builtin_amdgcn_global_load_lds(
                (const __attribute__((address_space(1))) unsigned int*)
                    (Bb + (long)(n0 + w * 32 + j * 16 + srow) * 1024 + k0b + scol),
                (__attribute__((address_space(3))) unsigned int*)
                    (Bls + (w * 2 + j) * 1024),
                16, 0, 0);
        __syncthreads();

        short8 a[2], b[4];
        #pragma unroll
        for (int i = 0; i < 2; ++i)
            a[i] = *(const short8*)(Als + (wm * 32 + i * 16 + lr) * 64 + hi * 16);
        #pragma unroll
        for (int j = 0; j < 4; ++j)
            b[j] = *(const short8*)(Bls + (wn * 64 + j * 16 + lr) * 64 + hi * 16);
        #pragma unroll
        for (int i = 0; i < 2; ++i)
            #pragma unroll
            for (int j = 0; j < 4; ++j)
                acc[i][j] = __builtin_amdgcn_mfma_f32_16x16x32_bf16(
                    a[i], b[j], acc[i][j], 0, 0, 0);
    }

    #pragma unroll
    for (int i = 0; i < 2; ++i)
        #pragma unroll
        for (int j = 0; j < 4; ++j) {
            const int u = n0 + wn * 64 + j * 16 + lr;
            const float bi = bias[u];
            #pragma unroll
            for (int q = 0; q < 4; ++q)
                C[(long)(m0 + wm * 32 + i * 16 + hi * 4 + q) * N3 + u]
                    = acc[i][j][q] + bi;
        }
}

// MX partial GEMM node: grid (12, NBY). blockIdx.y*64 rows. (chunks 0..1: NBY=8)
__global__ __launch_bounds__(256)
void gemm_mx(const __hip_bfloat16* __restrict__ A,
             const __hip_bfloat16* __restrict__ Bt,
             const float* __restrict__ bias,
             float* __restrict__ C)
{
    __shared__ char Als[4096];
    __shared__ char Bls[8192];
    gemm_tile_dev(A, Bt, bias, C, blockIdx.y * 64, blockIdx.x * 128, Als, Bls);
}

// Step 0 (h==0) + gemm chunk 2. Blocks [0,512) elementwise; [512,560) gemm.
__global__ __launch_bounds__(256)
void gru_step0g(const float* __restrict__ MX0,        // [256][1536] f32
                const float* __restrict__ rbias,      // [1536]
                float* __restrict__ hf_out,           // [256][512] f32
                char* __restrict__ hb_out,            // [256 rows][1024B] swz
                const __hip_bfloat16* __restrict__ Xb,
                const __hip_bfloat16* __restrict__ Kt,
                const float* __restrict__ ibias,
                float* __restrict__ MX)
{
    __shared__ char GA[4096];
    __shared__ char GB[8192];
    if (blockIdx.x >= 512) {
        const int g = blockIdx.x - 512;        // 0..47
        const int gx = g % 12, gy = g / 12;    // n-blk, m-blk
        gemm_tile_dev(Xb, Kt, ibias, MX, 2 * 256 + gy * 64, gx * 128, GA, GB);
        return;
    }
    const int idx = blockIdx.x * 256 + threadIdx.x;   // b*512 + u
    const int b = idx >> 9;
    const int u = idx & 511;
    const float* mx = MX0 + (long)b * N3;
    const float z = sigmoidf_(mx[u]          + rbias[u]);
    const float r = sigmoidf_(mx[u + UU]     + rbias[u + UU]);
    const float cand = mx[u + 2 * UU] + r * rbias[u + 2 * UU];
    const float hh = fmaxf(cand, 0.0f);
    const float hn = (1.0f - z) * hh;
    hf_out[idx] = hn;
    union { __hip_bfloat16 bf; unsigned short s; } cv;
    cv.bf = __float2bfloat16(hn);
    *(unsigned short*)(hb_out + (long)b * 1024 + ((u * 2) ^ ((b & 7) << 4))) = cv.s;
}

// One GRU step (r21 body) + gemm chunk cg. Blocks [0,128) step; [128,176) gemm.
// Used for steps 1..5 (never last -> always writes hb/hf).
__global__ __launch_bounds__(256)
void gru_stepg(const __hip_bfloat16* __restrict__ Rt,   // [1536][512] bf16
               const float* __restrict__ rbias,         // [1536]
               const float* __restrict__ MXc,           // [256][1536] f32 chunk c
               const char* __restrict__ hb_in,          // [256 rows][1024B] swz
               const float* __restrict__ hf_in,         // [256][512] f32
               char* __restrict__ hb_out,
               float* __restrict__ hf_out,
               const __hip_bfloat16* __restrict__ Xb,
               const __hip_bfloat16* __restrict__ Kt,
               const float* __restrict__ ibias,
               float* __restrict__ MX,
               int cg)
{
    __shared__ char Bls[96 * 1024];     // B slice, source-swizzled
    __shared__ char Als[32 * 1024];     // h rows (32 x 1KB), source-swizzled
    __shared__ char MXls[12288];        // [gate][32 rows][32 cols] f32
    if (blockIdx.x >= 128) {
        const int g = blockIdx.x - 128;        // 0..47
        const int gx = g % 12, gy = g / 12;
        gemm_tile_dev(Xb, Kt, ibias, MX, cg * 256 + gy * 64, gx * 128, Als, Bls);
        return;
    }
    const int tid = threadIdx.x;
    const int lane = tid & 63;
    const int w = tid >> 6;             // wave 0..3
    const int wy = w >> 1, wx = w & 1;
    const int by = blockIdx.x & 7;
    const int bx = blockIdx.x >> 3;
    const int lr = lane & 15;
    const int hi = lane >> 4;           // 0..3
    const int m0 = by * 32 + wy * 16;
    const int n0 = bx * 32;
    const int u  = n0 + wx * 16 + lr;

    // ---- Stage B-slice (96 rows x 1024B, r13-proven).
    {
        const char* RtB = (const char*)Rt;
        #pragma unroll
        for (int i = 0; i < 24; ++i) {
            const int j  = i * 4 + w;
            const int gt = j >> 5, cc = j & 31;
            const long srcoff = (long)(gt * 512 + n0 + cc) * 1024
                              + ((lane * 16) ^ ((j & 7) << 4));
            __builtin_amdgcn_global_load_lds(
                (const __attribute__((address_space(1))) unsigned int*)(RtB + srcoff),
                (__attribute__((address_space(3))) unsigned int*)(Bls + (long)j * 1024),
                16, 0, 0);
        }
    }
    // ---- Stage A (h rows, 32 x 1KB).
    #pragma unroll
    for (int i = 0; i < 8; ++i) {
        const int j = i * 4 + w;
        __builtin_amdgcn_global_load_lds(
            (const __attribute__((address_space(1))) unsigned int*)
                (hb_in + (long)(by * 32 + j) * 1024 + lane * 16),
            (__attribute__((address_space(3))) unsigned int*)(Als + (long)j * 1024),
            16, 0, 0);
    }
    // ---- Stage MX patch (gather-DMA, r17-proven).
    {
        const char* MXb = (const char*)MXc;
        #pragma unroll
        for (int jj = 0; jj < 3; ++jj) {
            const int k = w + 4 * jj;              // 0..11
            const int gt = k >> 2, rblk = k & 3;
            const long src = (long)(by * 32 + rblk * 8 + (lane >> 3)) * 6144
                           + gt * 2048 + bx * 128 + (lane & 7) * 16;
            __builtin_amdgcn_global_load_lds(
                (const __attribute__((address_space(1))) unsigned int*)(MXb + src),
                (__attribute__((address_space(3))) unsigned int*)
                    (MXls + gt * 4096 + rblk * 1024),
                16, 0, 0);
        }
    }

    float hold[4];
    #pragma unroll
    for (int q = 0; q < 4; ++q)
        hold[q] = hf_in[(long)(m0 + hi * 4 + q) * UU + u];
    const float rbz = rbias[u];
    const float rbg = rbias[u + UU];
    const float rbh = rbias[u + 2 * UU];

    __syncthreads();   // drains all DMAs (vmcnt(0) before s_barrier)

    f32x4 acc[3] = {{0.f,0.f,0.f,0.f},{0.f,0.f,0.f,0.f},{0.f,0.f,0.f,0.f}};
    #pragma unroll
    for (int kk = 0; kk < 16; ++kk) {
        const short8 a = *(const short8*)(Als + (wy * 16 + lr) * 1024
            + ((kk * 64 + hi * 16) ^ ((lr & 7) << 4)));
        #pragma unroll
        for (int gt = 0; gt < 3; ++gt) {
            const short8 b = *(const short8*)(Bls
                + (long)(gt * 32 + wx * 16 + lr) * 1024
                + ((kk * 64 + hi * 16) ^ ((lr & 7) << 4)));
            acc[gt] = __builtin_amdgcn_mfma_f32_16x16x32_bf16(a, b, acc[gt], 0, 0, 0);
        }
    }

    #pragma unroll
    for (int q = 0; q < 4; ++q) {
        const int rloc = wy * 16 + hi * 4 + q;     // 0..31
        const float xz = *(const float*)(MXls + 0 * 4096 + rloc * 128 + (wx * 16 + lr) * 4);
        const float xr = *(const float*)(MXls + 1 * 4096 + rloc * 128 + (wx * 16 + lr) * 4);
        const float xh = *(const float*)(MXls + 2 * 4096 + rloc * 128 + (wx * 16 + lr) * 4);
        const float z = sigmoidf_(xz + acc[0][q] + rbz);
        const float r = sigmoidf_(xr + acc[1][q] + rbg);
        const float cand = xh + r * (acc[2][q] + rbh);   // reset_after
        const float hh = fmaxf(cand, 0.0f);              // relu
        const float hn = z * hold[q] + (1.0f - z) * hh;
        const int m = m0 + hi * 4 + q;
        union { __hip_bfloat16 bf; unsigned short s; } cv;
        cv.bf = __float2bfloat16(hn);
        *(unsigned short*)(hb_out + (long)m * 1024
            + ((u * 2) ^ ((m & 7) << 4))) = cv.s;
        hf_out[(long)m * UU + u] = hn;
    }
}

// One GRU step, DMA-staged body. BYTE-IDENTICAL to r21's gru_step (steps 6,7).
__global__ __launch_bounds__(256)
void gru_step(const __hip_bfloat16* __restrict__ Rt,   // [1536][512] bf16
              const float* __restrict__ rbias,         // [1536]
              const float* __restrict__ MXc,           // [256][1536] f32 chunk c
              const char* __restrict__ hb_in,          // [256 rows][1024B] swz
              const float* __restrict__ hf_in,         // [256][512] f32
              char* __restrict__ hb_out,
              float* __restrict__ hf_out,
              float* __restrict__ out,                 // [256][512] f32
              int last)
{
    __shared__ char Bls[96 * 1024];     // B slice, source-swizzled
    __shared__ char Als[32 * 1024];     // h rows (32 x 1KB), source-swizzled
    __shared__ char MXls[12288];        // [gate][32 rows][32 cols] f32
    const int tid = threadIdx.x;
    const int lane = tid & 63;
    const int w = tid >> 6;             // wave 0..3
    const int wy = w >> 1, wx = w & 1;
    const int by = blockIdx.x & 7;
    const int bx = blockIdx.x >> 3;
    const int lr = lane & 15;
    const int hi = lane >> 4;           // 0..3
    const int m0 = by * 32 + wy * 16;
    const int n0 = bx * 32;
    const int u  = n0 + wx * 16 + lr;

    // ---- Stage B-slice (96 rows x 1024B, r13-proven).
    {
        const char* RtB = (const char*)Rt;
        #pragma unroll
        for (int i = 0; i < 24; ++i) {
            const int j  = i * 4 + w;
            const int gt = j >> 5, cc = j & 31;
            const long srcoff = (long)(gt * 512 + n0 + cc) * 1024
                              + ((lane * 16) ^ ((j & 7) << 4));
            __builtin_amdgcn_global_load_lds(
                (const __attribute__((address_space(1))) unsigned int*)(RtB + srcoff),
                (__attribute__((address_space(3))) unsigned int*)(Bls + (long)j * 1024),
                16, 0, 0);
        }
    }
    // ---- Stage A (h rows, 32 x 1KB).
    #pragma unroll
    for (int i = 0; i < 8; ++i) {
        const int j = i * 4 + w;
        __builtin_amdgcn_global_load_lds(
            (const __attribute__((address_space(1))) unsigned int*)
                (hb_in + (long)(by * 32 + j) * 1024 + lane * 16),
            (__attribute__((address_space(3))) unsigned int*)(Als + (long)j * 1024),
            16, 0, 0);
    }
    // ---- Stage MX patch (gather-DMA, r17-proven).
    {
        const char* MXb = (const char*)MXc;
        #pragma unroll
        for (int jj = 0; jj < 3; ++jj) {
            const int k = w + 4 * jj;              // 0..11
            const int gt = k >> 2, rblk = k & 3;
            const long src = (long)(by * 32 + rblk * 8 + (lane >> 3)) * 6144
                           + gt * 2048 + bx * 128 + (lane & 7) * 16;
            __builtin_amdgcn_global_load_lds(
                (const __attribute__((address_space(1))) unsigned int*)(MXb + src),
                (__attribute__((address_space(3))) unsigned int*)
                    (MXls + gt * 4096 + rblk * 1024),
                16, 0, 0);
        }
    }

    // hold (f32 carry) + rbias: scalar loads in flight under the DMA drain.
    float hold[4];
    #pragma unroll
    for (int q = 0; q < 4; ++q)
        hold[q] = hf_in[(long)(m0 + hi * 4 + q) * UU + u];
    const float rbz = rbias[u];
    const float rbg = rbias[u + UU];
    const float rbh = rbias[u + 2 * UU];

    __syncthreads();   // drains all DMAs (vmcnt(0) before s_barrier)

    f32x4 acc[3] = {{0.f,0.f,0.f,0.f},{0.f,0.f,0.f,0.f},{0.f,0.f,0.f,0.f}};
    #pragma unroll
    for (int kk = 0; kk < 16; ++kk) {
        const short8 a = *(const short8*)(Als + (wy * 16 + lr) * 1024
            + ((kk * 64 + hi * 16) ^ ((lr & 7) << 4)));
        #pragma unroll
        for (int gt = 0; gt < 3; ++gt) {
            const short8 b = *(const short8*)(Bls
                + (long)(gt * 32 + wx * 16 + lr) * 1024
                + ((kk * 64 + hi * 16) ^ ((lr & 7) << 4)));
            acc[gt] = __builtin_amdgcn_mfma_f32_16x16x32_bf16(a, b, acc[gt], 0, 0, 0);
        }
    }

    #pragma unroll
    for (int q = 0; q < 4; ++q) {
        const int rloc = wy * 16 + hi * 4 + q;     // 0..31
        const float xz = *(const float*)(MXls + 0 * 4096 + rloc * 128 + (wx * 16 + lr) * 4);
        const float xr = *(const float*)(MXls + 1 * 4096 + rloc * 128 + (wx * 16 + lr) * 4);
        const float xh = *(const float*)(MXls + 2 * 4096 + rloc * 128 + (wx * 16 + lr) * 4);
        const float z = sigmoidf_(xz + acc[0][q] + rbz);
        const float r = sigmoidf_(xr + acc[1][q] + rbg);
        const float cand = xh + r * (acc[2][q] + rbh);   // reset_after
        const float hh = fmaxf(cand, 0.0f);              // relu
        const float hn = z * hold[q] + (1.0f - z) * hh;
        const int m = m0 + hi * 4 + q;
        if (!last) {
            union { __hip_bfloat16 bf; unsigned short s; } cv;
            cv.bf = __float2bfloat16(hn);
            *(unsigned short*)(hb_out + (long)m * 1024
                + ((u * 2) ^ ((m & 7) << 4))) = cv.s;
            hf_out[(long)m * UU + u] = hn;
        } else {
            out[(long)m * UU + u] = hn;
        }
    }
}

extern "C" void kernel_launch(void* const* d_in, const int* in_sizes, int n_in,
                              void* d_out, int out_size, void* d_ws, size_t ws_size,
                              hipStream_t stream)
{
    const float* x     = (const float*)d_in[0];   // [256,192,512]
    const float* ker   = (const float*)d_in[1];   // [512,1536]
    const float* rker  = (const float*)d_in[2];   // [512,1536]
    const float* ibias = (const float*)d_in[3];   // [1536]
    const float* rbias = (const float*)d_in[4];   // [1536]
    float* out = (float*)d_out;                   // [256,512]

    char* ws = (char*)d_ws;
    float*          MX   = (float*)ws;                            // 12,582,912 B
    __hip_bfloat16* Xb   = (__hip_bfloat16*)(ws + 12582912);      //  2,097,152 B
    __hip_bfloat16* Kt   = (__hip_bfloat16*)(ws + 14680064);      //  1,572,864 B
    __hip_bfloat16* Rt   = (__hip_bfloat16*)(ws + 16252928);      //  1,572,864 B
    char*           hb0  = (char*)(ws + 17825792);                //    262,144 B
    char*           hb1  = (char*)(ws + 18087936);                //    262,144 B
    // hf carry buffers live past Xb's hot region? Xb is read by the riding
    // gemm WGs through step 5 -> hf buffers get their own space instead:
    float*          hf0  = (float*)(ws + 18350080);               //    524,288 B
    float*          hf1  = (float*)(ws + 18874368);               //    524,288 B

    // Node 1: fused prologue (2 transposes + x gather/convert)
    prologue<<<2048, 256, 0, stream>>>(ker, rker, x, Kt, Rt, Xb);

    // Node 2: MX chunks 0-1 only (rows 0..511), grid (12,8) = 96 WGs.
    gemm_mx<<<dim3(N3 / 128, 8), 256, 0, stream>>>(Xb, Kt, ibias, MX);

    // Node 3: step 0 (elementwise) + gemm chunk 2 riding along.
    gru_step0g<<<560, 256, 0, stream>>>(MX, rbias, hf1, hb1,
                                        Xb, Kt, ibias, MX);

    // Nodes 4-8: steps 1..5, each carrying gemm chunk c+2 (48 extra WGs).
    for (int c = 1; c <= 5; ++c) {
        const char*  hb_in = (c & 1) ? hb1 : hb0;
        const float* hf_in = (c & 1) ? hf1 : hf0;
        char*  hb_o = (c & 1) ? hb0 : hb1;
        float* hf_o = (c & 1) ? hf0 : hf1;
        gru_stepg<<<176, 256, 0, stream>>>(
            Rt, rbias, MX + (long)c * BB * N3, hb_in, hf_in,
            hb_o, hf_o, Xb, Kt, ibias, MX, c + 2);
    }

    // Nodes 9-10: steps 6,7 (untouched r21 kernel).
    for (int c = 6; c < 8; ++c) {
        const char*  hb_in = (c & 1) ? hb1 : hb0;
        const float* hf_in = (c & 1) ? hf1 : hf0;
        char*  hb_o = (c & 1) ? hb0 : hb1;
        float* hf_o = (c & 1) ? hf0 : hf1;
        gru_step<<<128, 256, 0, stream>>>(
            Rt, rbias, MX + (long)c * BB * N3, hb_in, hf_in,
            hb_o, hf_o, out, (c == 7) ? 1 : 0);
    }
}

// Round 25
// 57.804 us; speedup vs baseline: 1.4232x; 1.4232x over previous
//
#include <hip/hip_runtime.h>
#include <hip/hip_bf16.h>
#include <math.h>

// SkipGRU on MI355X, round 25: REVERT to r21 — the measured optimum (58.0us).
// r22 (+8.5), r23 (+9), r24 (+24) all falsified attempts to shave the last
// ~10us: step-fusion pays the per-thread-load law (~0.1us/load x 96), riding
// gemm WGs pay per-kernel LDS reservation (140KB -> serialized tail).
// Final decomposition: 8 x ~3us kernel-boundary sync (cheapest of 7 measured
// sync mechanisms) + ~12us DMA-staged step bodies + ~20us fixed
// (prologue/gemm/gaps). This is a latency-structure floor, not a
// counter roofline. Session: 289 -> 58us.
//
// Only chain j=23 contributes to outputs[:, -1, :] (t=191 = chunk 7 lane 23):
// 8 sequential GRU steps over x[:, c*24+23, :], h[256,512].
//
// mfma_f32_16x16x32_bf16 layouts (learn_hip m89-verified, r4-r24 validated):
//   A: lane l holds A[l&15][(l>>4)*8 + j]
//   B: lane l holds B[(l>>4)*8 + j][l&15]  (B^T row-major -> contiguous load)
//   D: lane l reg q -> row (l>>4)*4+q, col l&15
//
// Swizzle rule (h and B): global row of 1024B stores byte o at o^((row&7)<<4);
// global_load_lds copies rows linearly; ds_read applies the same XOR
// (involution) -> conflict-free LDS reads (guide §6 G4 + m173; r13-r21 proven).

typedef float f32x4 __attribute__((ext_vector_type(4)));
typedef short short8 __attribute__((ext_vector_type(8)));

#define BB 256
#define UU 512
#define KK 512
#define N3 1536

__device__ __forceinline__ float sigmoidf_(float s) {
    return 1.0f / (1.0f + __expf(-s));
}

// Fused prologue: blocks [0,768) transpose ker, [768,1536) transpose rker,
// [1536,2048) gather+convert x.
__global__ __launch_bounds__(256)
void prologue(const float* __restrict__ ker, const float* __restrict__ rker,
              const float* __restrict__ x,
              __hip_bfloat16* __restrict__ Kt, __hip_bfloat16* __restrict__ Rtb,
              __hip_bfloat16* __restrict__ Xb)
{
    __shared__ float tile[32][33];
    const int blk = blockIdx.x;
    const int tid = threadIdx.x;
    if (blk < 1536) {
        const float* W = (blk < 768) ? ker : rker;
        __hip_bfloat16* Wt = (blk < 768) ? Kt : Rtb;
        const int b = (blk < 768) ? blk : blk - 768;
        const int xx = tid & 31, yy = tid >> 5;           // (32, 8)
        const int c0 = (b % 48) * 32;                     // C = 1536
        const int r0 = (b / 48) * 32;                     // R = 512
        #pragma unroll
        for (int i = 0; i < 32; i += 8)
            tile[yy + i][xx] = W[(long)(r0 + yy + i) * N3 + c0 + xx];
        __syncthreads();
        #pragma unroll
        for (int i = 0; i < 32; i += 8)
            Wt[(long)(c0 + yy + i) * KK + r0 + xx] = __float2bfloat16(tile[xx][yy + i]);
    } else {
        const int idx = (blk - 1536) * 256 + tid;         // one thread per 8 elems
        const int e = idx * 8;
        const int m = e >> 9;              // 0..2047 = c*256+b
        const int kk = e & 511;
        const int bb = m & 255, c = m >> 8;
        const float* src = x + (long)bb * (192 * 512) + (long)(c * 24 + 23) * 512 + kk;
        float4 v0 = *(const float4*)src;
        float4 v1 = *(const float4*)(src + 4);
        __hip_bfloat16* dst = Xb + (long)m * 512 + kk;
        dst[0] = __float2bfloat16(v0.x);
        dst[1] = __float2bfloat16(v0.y);
        dst[2] = __float2bfloat16(v0.z);
        dst[3] = __float2bfloat16(v0.w);
        dst[4] = __float2bfloat16(v1.x);
        dst[5] = __float2bfloat16(v1.y);
        dst[6] = __float2bfloat16(v1.z);
        dst[7] = __float2bfloat16(v1.w);
    }
}

// MX = A @ Bt^T + bias. 64x128 tile, BK=32, grid (12,32)=384 WGs.
__global__ __launch_bounds__(256)
void gemm_mx(const __hip_bfloat16* __restrict__ A,
             const __hip_bfloat16* __restrict__ Bt,
             const float* __restrict__ bias,
             float* __restrict__ C)
{
    __shared__ char Als[4096];
    __shared__ char Bls[8192];
    const int tid = threadIdx.x;
    const int lane = tid & 63;
    const int w = tid >> 6;
    const int wm = w >> 1, wn = w & 1;
    const int m0 = blockIdx.y * 64;
    const int n0 = blockIdx.x * 128;
    const int lr = lane & 15;
    const int hi = lane >> 4;

    const int srow = lane >> 2;
    const int scol = (lane & 3) * 16;

    const char* Ab = (const char*)A;
    const char* Bb = (const char*)Bt;

    f32x4 acc[2][4];
    #pragma unroll
    for (int i = 0; i < 2; ++i)
        #pragma unroll
        for (int j = 0; j < 4; ++j) acc[i][j] = {0.f, 0.f, 0.f, 0.f};

    for (int ks = 0; ks < 16; ++ks) {
        const long k0b = (long)ks * 64;
        __syncthreads();
        __builtin_amdgcn_global_load_lds(
            (const __attribute__((address_space(1))) unsigned int*)
                (Ab + (long)(m0 + w * 16 + srow) * 1024 + k0b + scol),
            (__attribute__((address_space(3))) unsigned int*)(Als + w * 1024),
            16, 0, 0);
        #pragma unroll
        for (int j = 0; j < 2; ++j)
            __builtin_amdgcn_global_load_lds(
                (const __attribute__((address_space(1))) unsigned int*)
                    (Bb + (long)(n0 + w * 32 + j * 16 + srow) * 1024 + k0b + scol),
                (__attribute__((address_space(3))) unsigned int*)
                    (Bls + (w * 2 + j) * 1024),
                16, 0, 0);
        __syncthreads();

        short8 a[2], b[4];
        #pragma unroll
        for (int i = 0; i < 2; ++i)
            a[i] = *(const short8*)(Als + (wm * 32 + i * 16 + lr) * 64 + hi * 16);
        #pragma unroll
        for (int j = 0; j < 4; ++j)
            b[j] = *(const short8*)(Bls + (wn * 64 + j * 16 + lr) * 64 + hi * 16);
        #pragma unroll
        for (int i = 0; i < 2; ++i)
            #pragma unroll
            for (int j = 0; j < 4; ++j)
                acc[i][j] = __builtin_amdgcn_mfma_f32_16x16x32_bf16(
                    a[i], b[j], acc[i][j], 0, 0, 0);
    }

    #pragma unroll
    for (int i = 0; i < 2; ++i)
        #pragma unroll
        for (int j = 0; j < 4; ++j) {
            const int u = n0 + wn * 64 + j * 16 + lr;
            const float bi = bias[u];
            #pragma unroll
            for (int q = 0; q < 4; ++q)
                C[(long)(m0 + wm * 32 + i * 16 + hi * 4 + q) * N3 + u]
                    = acc[i][j][q] + bi;
        }
}

// Step 0 (h==0): mi = rbias, pure elementwise. Writes f32 hf + swizzled bf16.
__global__ __launch_bounds__(256)
void gru_step0(const float* __restrict__ MX0,         // [256][1536] f32
               const float* __restrict__ rbias,       // [1536]
               float* __restrict__ hf_out,            // [256][512] f32
               char* __restrict__ hb_out)             // [256 rows][1024B] swz
{
    const int idx = blockIdx.x * 256 + threadIdx.x;   // b*512 + u
    const int b = idx >> 9;
    const int u = idx & 511;
    const float* mx = MX0 + (long)b * N3;
    const float z = sigmoidf_(mx[u]          + rbias[u]);
    const float r = sigmoidf_(mx[u + UU]     + rbias[u + UU]);
    const float cand = mx[u + 2 * UU] + r * rbias[u + 2 * UU];
    const float hh = fmaxf(cand, 0.0f);
    const float hn = (1.0f - z) * hh;
    hf_out[idx] = hn;
    union { __hip_bfloat16 bf; unsigned short s; } cv;
    cv.bf = __float2bfloat16(hn);
    *(unsigned short*)(hb_out + (long)b * 1024 + ((u * 2) ^ ((b & 7) << 4))) = cv.s;
}

// One GRU step, DMA-staged body (r17/r20-proven). 128 WGs x 256 thr.
// WG (by=blockIdx&7, bx=blockIdx>>3): rows by*32..+32, cols bx*32..+32.
__global__ __launch_bounds__(256)
void gru_step(const __hip_bfloat16* __restrict__ Rt,   // [1536][512] bf16
              const float* __restrict__ rbias,         // [1536]
              const float* __restrict__ MXc,           // [256][1536] f32 chunk c
              const char* __restrict__ hb_in,          // [256 rows][1024B] swz
              const float* __restrict__ hf_in,         // [256][512] f32
              char* __restrict__ hb_out,
              float* __restrict__ hf_out,
              float* __restrict__ out,                 // [256][512] f32
              int last)
{
    __shared__ char Bls[96 * 1024];     // B slice, source-swizzled
    __shared__ char Als[32 * 1024];     // h rows (32 x 1KB), source-swizzled
    __shared__ char MXls[12288];        // [gate][32 rows][32 cols] f32
    const int tid = threadIdx.x;
    const int lane = tid & 63;
    const int w = tid >> 6;             // wave 0..3
    const int wy = w >> 1, wx = w & 1;
    const int by = blockIdx.x & 7;
    const int bx = blockIdx.x >> 3;
    const int lr = lane & 15;
    const int hi = lane >> 4;           // 0..3
    const int m0 = by * 32 + wy * 16;
    const int n0 = bx * 32;
    const int u  = n0 + wx * 16 + lr;

    // ---- Stage B-slice (96 rows x 1024B, r13-proven).
    {
        const char* RtB = (const char*)Rt;
        #pragma unroll
        for (int i = 0; i < 24; ++i) {
            const int j  = i * 4 + w;
            const int gt = j >> 5, cc = j & 31;
            const long srcoff = (long)(gt * 512 + n0 + cc) * 1024
                              + ((lane * 16) ^ ((j & 7) << 4));
            __builtin_amdgcn_global_load_lds(
                (const __attribute__((address_space(1))) unsigned int*)(RtB + srcoff),
                (__attribute__((address_space(3))) unsigned int*)(Bls + (long)j * 1024),
                16, 0, 0);
        }
    }
    // ---- Stage A (h rows, 32 x 1KB).
    #pragma unroll
    for (int i = 0; i < 8; ++i) {
        const int j = i * 4 + w;
        __builtin_amdgcn_global_load_lds(
            (const __attribute__((address_space(1))) unsigned int*)
                (hb_in + (long)(by * 32 + j) * 1024 + lane * 16),
            (__attribute__((address_space(3))) unsigned int*)(Als + (long)j * 1024),
            16, 0, 0);
    }
    // ---- Stage MX patch (gather-DMA, r17-proven).
    {
        const char* MXb = (const char*)MXc;
        #pragma unroll
        for (int jj = 0; jj < 3; ++jj) {
            const int k = w + 4 * jj;              // 0..11
            const int gt = k >> 2, rblk = k & 3;
            const long src = (long)(by * 32 + rblk * 8 + (lane >> 3)) * 6144
                           + gt * 2048 + bx * 128 + (lane & 7) * 16;
            __builtin_amdgcn_global_load_lds(
                (const __attribute__((address_space(1))) unsigned int*)(MXb + src),
                (__attribute__((address_space(3))) unsigned int*)
                    (MXls + gt * 4096 + rblk * 1024),
                16, 0, 0);
        }
    }

    // hold (f32 carry) + rbias: scalar loads in flight under the DMA drain.
    float hold[4];
    #pragma unroll
    for (int q = 0; q < 4; ++q)
        hold[q] = hf_in[(long)(m0 + hi * 4 + q) * UU + u];
    const float rbz = rbias[u];
    const float rbg = rbias[u + UU];
    const float rbh = rbias[u + 2 * UU];

    __syncthreads();   // drains all DMAs (vmcnt(0) before s_barrier)

    f32x4 acc[3] = {{0.f,0.f,0.f,0.f},{0.f,0.f,0.f,0.f},{0.f,0.f,0.f,0.f}};
    #pragma unroll
    for (int kk = 0; kk < 16; ++kk) {
        const short8 a = *(const short8*)(Als + (wy * 16 + lr) * 1024
            + ((kk * 64 + hi * 16) ^ ((lr & 7) << 4)));
        #pragma unroll
        for (int gt = 0; gt < 3; ++gt) {
            const short8 b = *(const short8*)(Bls
                + (long)(gt * 32 + wx * 16 + lr) * 1024
                + ((kk * 64 + hi * 16) ^ ((lr & 7) << 4)));
            acc[gt] = __builtin_amdgcn_mfma_f32_16x16x32_bf16(a, b, acc[gt], 0, 0, 0);
        }
    }

    #pragma unroll
    for (int q = 0; q < 4; ++q) {
        const int rloc = wy * 16 + hi * 4 + q;     // 0..31
        const float xz = *(const float*)(MXls + 0 * 4096 + rloc * 128 + (wx * 16 + lr) * 4);
        const float xr = *(const float*)(MXls + 1 * 4096 + rloc * 128 + (wx * 16 + lr) * 4);
        const float xh = *(const float*)(MXls + 2 * 4096 + rloc * 128 + (wx * 16 + lr) * 4);
        const float z = sigmoidf_(xz + acc[0][q] + rbz);
        const float r = sigmoidf_(xr + acc[1][q] + rbg);
        const float cand = xh + r * (acc[2][q] + rbh);   // reset_after
        const float hh = fmaxf(cand, 0.0f);              // relu
        const float hn = z * hold[q] + (1.0f - z) * hh;
        const int m = m0 + hi * 4 + q;
        if (!last) {
            union { __hip_bfloat16 bf; unsigned short s; } cv;
            cv.bf = __float2bfloat16(hn);
            *(unsigned short*)(hb_out + (long)m * 1024
                + ((u * 2) ^ ((m & 7) << 4))) = cv.s;
            hf_out[(long)m * UU + u] = hn;
        } else {
            out[(long)m * UU + u] = hn;
        }
    }
}

extern "C" void kernel_launch(void* const* d_in, const int* in_sizes, int n_in,
                              void* d_out, int out_size, void* d_ws, size_t ws_size,
                              hipStream_t stream)
{
    const float* x     = (const float*)d_in[0];   // [256,192,512]
    const float* ker   = (const float*)d_in[1];   // [512,1536]
    const float* rker  = (const float*)d_in[2];   // [512,1536]
    const float* ibias = (const float*)d_in[3];   // [1536]
    const float* rbias = (const float*)d_in[4];   // [1536]
    float* out = (float*)d_out;                   // [256,512]

    char* ws = (char*)d_ws;
    float*          MX   = (float*)ws;                            // 12,582,912 B
    __hip_bfloat16* Xb   = (__hip_bfloat16*)(ws + 12582912);      //  2,097,152 B
    __hip_bfloat16* Kt   = (__hip_bfloat16*)(ws + 14680064);      //  1,572,864 B
    __hip_bfloat16* Rt   = (__hip_bfloat16*)(ws + 16252928);      //  1,572,864 B
    char*           hb0  = (char*)(ws + 17825792);                //    262,144 B
    char*           hb1  = (char*)(ws + 18087936);                //    262,144 B
    // hf carry buffers reuse Xb's space (dead after gemm_mx):
    float*          hf0  = (float*)(ws + 12582912);               //    524,288 B
    float*          hf1  = (float*)(ws + 13107200);               //    524,288 B

    // Node 1: fused prologue (2 transposes + x gather/convert)
    prologue<<<2048, 256, 0, stream>>>(ker, rker, x, Kt, Rt, Xb);

    // Node 2: MX = Xsel @ kernel + input_bias (64x128 tile, 384 WGs)
    gemm_mx<<<dim3(N3 / 128, 2048 / 64), 256, 0, stream>>>(Xb, Kt, ibias, MX);

    // Node 3: step 0 (h0 == 0 -> elementwise); writes hf1/hb1.
    gru_step0<<<512, 256, 0, stream>>>(MX, rbias, hf1, hb1);

    // Nodes 4-10: steps 1..7, kernel-per-step, DMA-staged bodies.
    for (int c = 1; c < 8; ++c) {
        const char*  hb_in = (c & 1) ? hb1 : hb0;
        const float* hf_in = (c & 1) ? hf1 : hf0;
        char*  hb_o = (c & 1) ? hb0 : hb1;
        float* hf_o = (c & 1) ? hf0 : hf1;
        gru_step<<<128, 256, 0, stream>>>(
            Rt, rbias, MX + (long)c * BB * N3, hb_in, hf_in,
            hb_o, hf_o, out, (c == 7) ? 1 : 0);
    }
}